// Round 9
// baseline (259.940 us; speedup 1.0000x reference)
//
#include <hip/hip_runtime.h>
#include <hip/hip_bf16.h>

// ---------------------------------------------------------------------------
// CausalSelfAttention: y = proj( softmax_causal( (xWqkv+b).q @ k^T / 8 ) @ v )
// B=4, T=2048, C=1024, H=16, D=64.  bf16 MFMA compute, fp32 accumulate.
// ---------------------------------------------------------------------------

typedef __attribute__((ext_vector_type(8)))  __bf16 bf16x8;
typedef __attribute__((ext_vector_type(2)))  float  f32x2;
typedef __attribute__((ext_vector_type(4)))  float  f32x4;
typedef __attribute__((ext_vector_type(16))) float  f32x16;
typedef __attribute__((ext_vector_type(4)))  unsigned int u32x4;

#define AS1C(p) ((const __attribute__((address_space(1))) unsigned int*)(p))
#define AS3(p)  ((__attribute__((address_space(3))) unsigned int*)(p))

__device__ __forceinline__ unsigned short f2bfu(float f){
  __hip_bfloat16 h = __float2bfloat16(f);
  return __builtin_bit_cast(unsigned short, h);
}

// v_permlane32_swap_b32: a.hi(lanes32-63) <-> b.lo(lanes0-31), both modified.
// ONLY safe when a and b hold distinct values (distinct vregs).
__device__ __forceinline__ void plswapu(unsigned int &a, unsigned int &b){
  asm("v_permlane32_swap_b32 %0, %1" : "+v"(a), "+v"(b));
}
// pack two f32 -> one u32 of 2 bf16 (lo = first arg)
__device__ __forceinline__ unsigned int cvtpk(float lo, float hi){
  unsigned int r;
  asm("v_cvt_pk_bf16_f32 %0, %1, %2" : "=v"(r) : "v"(lo), "v"(hi));
  return r;
}
__device__ __forceinline__ float max3f(float a, float b, float c){
  float r;
  asm("v_max3_f32 %0, %1, %2, %3" : "=v"(r) : "v"(a), "v"(b), "v"(c));
  return r;
}

// ---------------- conversion kernels ----------------

__global__ __launch_bounds__(256)
void f32_to_bf16_vec(const float* __restrict__ in, __hip_bfloat16* __restrict__ out, int n4){
  int stride = gridDim.x * blockDim.x;
  for (int i = blockIdx.x*blockDim.x + threadIdx.x; i < n4; i += stride){
    float4 v = reinterpret_cast<const float4*>(in)[i];
    ushort4 u;
    u.x = f2bfu(v.x); u.y = f2bfu(v.y); u.z = f2bfu(v.z); u.w = f2bfu(v.w);
    reinterpret_cast<ushort4*>(out)[i] = u;
  }
}

// in[R][C] fp32 -> out[C][R] bf16
__global__ __launch_bounds__(256)
void transpose_to_bf16(const float* __restrict__ in, __hip_bfloat16* __restrict__ out, int R, int C){
  __shared__ float tile[32][33];
  const int tx = threadIdx.x & 31, ty = threadIdx.x >> 5;
  const int c0 = blockIdx.x*32, r0 = blockIdx.y*32;
  for (int i = ty; i < 32; i += 8)
    tile[i][tx] = in[(size_t)(r0+i)*C + c0 + tx];
  __syncthreads();
  for (int i = ty; i < 32; i += 8)
    out[(size_t)(c0+i)*R + r0 + tx] = __float2bfloat16(tile[tx][i]);
}

// ---------------- bf16 GEMM (m97-style 128x128, BK=32) ----------------

#define QSCALE 0.1803368801111244f   // 0.125 * log2(e) -> softmax in exp2 space

template<int EPI>
__global__ __launch_bounds__(256)
void gemm_bf16(const __hip_bfloat16* __restrict__ A,
               const __hip_bfloat16* __restrict__ Bt,
               const float* __restrict__ bias,
               int M, int N, int K,
               __hip_bfloat16* __restrict__ q_s,
               __hip_bfloat16* __restrict__ k_s,
               __hip_bfloat16* __restrict__ vT_s,
               float* __restrict__ outf)
{
  __shared__ __align__(16) __hip_bfloat16 sA[128*32];
  __shared__ __align__(16) __hip_bfloat16 sB[128*32];
  const int tid = threadIdx.x, w = tid>>6, l = tid&63, g = l>>4, li = l&15;
  const int wm = w>>1, wn = w&1;

  const int nwg = gridDim.x, cpx = nwg >> 3;
  const int swz = (blockIdx.x & 7)*cpx + (blockIdx.x >> 3);
  const int nbx = N >> 7;
  const int m0 = (swz / nbx)*128, n0 = (swz % nbx)*128;

  f32x4 acc[4][4] = {};

  for (int k0 = 0; k0 < K; k0 += 32){
    __syncthreads();
    #pragma unroll
    for (int qq = 0; qq < 2; ++qq){
      const int c = qq*256 + w*64 + l;
      const int row = c>>2, kc = c&3;
      __builtin_amdgcn_global_load_lds(AS1C(A  + (size_t)(m0+row)*K + k0 + 8*kc),
                                       AS3(sA + (qq*256 + w*64)*8), 16, 0, 0);
      __builtin_amdgcn_global_load_lds(AS1C(Bt + (size_t)(n0+row)*K + k0 + 8*kc),
                                       AS3(sB + (qq*256 + w*64)*8), 16, 0, 0);
    }
    __syncthreads();

    bf16x8 af[4], bfr[4];
    #pragma unroll
    for (int mi = 0; mi < 4; ++mi)
      af[mi] = *reinterpret_cast<const bf16x8*>(sA + (wm*64 + mi*16 + li)*32 + 8*g);
    #pragma unroll
    for (int ni = 0; ni < 4; ++ni)
      bfr[ni] = *reinterpret_cast<const bf16x8*>(sB + (wn*64 + ni*16 + li)*32 + 8*g);
    #pragma unroll
    for (int mi = 0; mi < 4; ++mi)
      #pragma unroll
      for (int ni = 0; ni < 4; ++ni)
        acc[mi][ni] = __builtin_amdgcn_mfma_f32_16x16x32_bf16(af[mi], bfr[ni], acc[mi][ni], 0, 0, 0);
  }

  #pragma unroll
  for (int ni = 0; ni < 4; ++ni){
    const int col = n0 + wn*64 + ni*16 + li;
    const float bv = bias[col];
    #pragma unroll
    for (int mi = 0; mi < 4; ++mi){
      #pragma unroll
      for (int e = 0; e < 4; ++e){
        const int row = m0 + wm*64 + mi*16 + 4*g + e;
        const float val = acc[mi][ni][e] + bv;
        if (EPI == 0){
          const int three = col >> 10, h = (col >> 6) & 15, d = col & 63;
          const int b = row >> 11, t = row & 2047;
          const int bh = b*16 + h;
          if (three == 0)      q_s[((size_t)bh*2048 + t)*64 + d]  = __float2bfloat16(val*QSCALE);
          else if (three == 1) k_s[((size_t)bh*2048 + t)*64 + d]  = __float2bfloat16(val);
          else                 vT_s[((size_t)bh*64 + d)*2048 + t] = __float2bfloat16(val);  // V^T
        } else {
          outf[(size_t)row*N + col] = val;
        }
      }
    }
  }
}

// ---------------- flash attention ------------------------------------------
// R6 structure (4 waves, 128-row q-tile, pair (15-p, p), XCD-pinned bh) plus:
//  * 4-deep LDS ring, stage 2 tiles ahead, ONE barrier per step
//  * register-double-buffered S (sA/sB), softmax(j-1) overlaps QK(j) MFMA
//  * packed-f32 softmax (v_pk_add_f32) + v_max3_f32 max tree
//  * defer-max (THR=8 log2), setprio around MFMA clusters

__device__ __forceinline__ void stage_kv(const __hip_bfloat16* __restrict__ k_s,
                                         const __hip_bfloat16* __restrict__ vT_s,
                                         size_t base, int j,
                                         __hip_bfloat16* sk, __hip_bfloat16* svt,
                                         int w, int l)
{
  #pragma unroll
  for (int qq = 0; qq < 2; ++qq){
    const int c = qq*256 + w*64 + l;       // 16B chunk id (512 per 8KB tile)
    const int r = c>>3, cc = c&7;          // 8 chunks per 128B row
    __builtin_amdgcn_global_load_lds(AS1C(k_s  + base + (size_t)(j*64 + r)*64 + 8*(cc ^ (r&7))),
                                     AS3(sk  + (qq*256 + w*64)*8), 16, 0, 0);
    __builtin_amdgcn_global_load_lds(AS1C(vT_s + base + (size_t)r*2048 + j*64 + 8*(cc ^ (r&7))),
                                     AS3(svt + (qq*256 + w*64)*8), 16, 0, 0);
  }
}

__device__ __forceinline__ bf16x8 ldtile(const __hip_bfloat16* t, int row, int chunk){
  return *reinterpret_cast<const bf16x8*>(t + row*64 + ((chunk ^ (row&7))*8));
}

#define PFX(K) (((K)&1) ? pf2[(K)>>1].y : pf2[(K)>>1].x)

// softmax of tile jp (S in sp0/sp1) + PV accumulate from svt buffer
__device__ __forceinline__ void softmax_pv(
    int jp, int jd, int qabs, int h4, int lq, int h,
    const __hip_bfloat16* svtc,
    f32x16& sp0, f32x16& sp1,
    f32x16& o0, f32x16& o1, float& mrun, float& lrun)
{
  f32x2 pf2[16];
  #pragma unroll
  for (int i = 0; i < 8; ++i){
    pf2[i]     = (f32x2){ sp0[2*i], sp0[2*i+1] };
    pf2[8 + i] = (f32x2){ sp1[2*i], sp1[2*i+1] };
  }
  if (jp == jd){                      // causal mask, diagonal tile only
    const int rel = qabs - 64*jp;
    #pragma unroll
    for (int i = 0; i < 16; ++i){
      const int a = i >> 3;
      const int r0 = (i & 7)*2, r1 = r0 + 1;
      const int kv0 = 32*a + (r0&3) + 8*(r0>>2) + h4;
      const int kv1 = 32*a + (r1&3) + 8*(r1>>2) + h4;
      pf2[i].x = (kv0 <= rel) ? pf2[i].x : -1e30f;
      pf2[i].y = (kv1 <= rel) ? pf2[i].y : -1e30f;
    }
  }

  // max tree: v_max3 (17 ops)
  float t0 = max3f(PFX(0),PFX(1),PFX(2)),   t1 = max3f(PFX(3),PFX(4),PFX(5));
  float t2 = max3f(PFX(6),PFX(7),PFX(8)),   t3 = max3f(PFX(9),PFX(10),PFX(11));
  float t4 = max3f(PFX(12),PFX(13),PFX(14)),t5 = max3f(PFX(15),PFX(16),PFX(17));
  float t6 = max3f(PFX(18),PFX(19),PFX(20)),t7 = max3f(PFX(21),PFX(22),PFX(23));
  float t8 = max3f(PFX(24),PFX(25),PFX(26)),t9 = max3f(PFX(27),PFX(28),PFX(29));
  float t10 = fmaxf(PFX(30),PFX(31));
  float u0 = max3f(t0,t1,t2), u1 = max3f(t3,t4,t5), u2 = max3f(t6,t7,t8);
  float u3 = fmaxf(t9,t10);
  float pm = fmaxf(max3f(u0,u1,u2), u3);

  // defer-max (T13)
  if (!__all(pm - mrun <= 8.0f)){
    pm = fmaxf(pm, __shfl_xor(pm, 32));
    const float nm = fmaxf(mrun, pm);
    const float corr = exp2f(mrun - nm);
    mrun = nm;
    o0 *= corr; o1 *= corr;
    lrun *= corr;
  }

  // subtract (v_pk_add) + exp2
  const f32x2 negm = { -mrun, -mrun };
  #pragma unroll
  for (int i = 0; i < 16; ++i) pf2[i] = pf2[i] + negm;
  #pragma unroll
  for (int i = 0; i < 16; ++i){
    pf2[i].x = exp2f(pf2[i].x);
    pf2[i].y = exp2f(pf2[i].y);
  }

  // sum tree (v_pk_add, 15 ops) + cross-half combine
  f32x2 q8[8];
  #pragma unroll
  for (int i = 0; i < 8; ++i) q8[i] = pf2[i] + pf2[8+i];
  f32x2 q4a = q8[0]+q8[4], q4b = q8[1]+q8[5], q4c = q8[2]+q8[6], q4d = q8[3]+q8[7];
  f32x2 q2a = q4a+q4c, q2b = q4b+q4d;
  f32x2 q1 = q2a+q2b;
  float psum = q1.x + q1.y;
  psum += __shfl_xor(psum, 32);
  lrun += psum;

  // P -> bf16 B-frags (cvt_pk + permlane32_swap)
  unsigned int wds[16];
  #pragma unroll
  for (int k = 0; k < 16; ++k) wds[k] = cvtpk(pf2[k].x, pf2[k].y);
  #pragma unroll
  for (int a = 0; a < 2; ++a)
    #pragma unroll
    for (int bl = 0; bl < 2; ++bl){
      plswapu(wds[a*8 + 4*bl    ], wds[a*8 + 4*bl + 2]);
      plswapu(wds[a*8 + 4*bl + 1], wds[a*8 + 4*bl + 3]);
    }
  bf16x8 pfr[4];
  #pragma unroll
  for (int B = 0; B < 4; ++B){
    u32x4 t = { wds[4*B], wds[4*B+1], wds[4*B+2], wds[4*B+3] };
    pfr[B] = __builtin_bit_cast(bf16x8, t);
  }

  // PV swapped: O[d][q]
  __builtin_amdgcn_s_setprio(1);
  #pragma unroll
  for (int ks = 0; ks < 4; ++ks){
    bf16x8 vf0 = ldtile(svtc, lq,      2*ks + h);
    o0 = __builtin_amdgcn_mfma_f32_32x32x16_bf16(vf0, pfr[ks], o0, 0, 0, 0);
    bf16x8 vf1 = ldtile(svtc, 32 + lq, 2*ks + h);
    o1 = __builtin_amdgcn_mfma_f32_32x32x16_bf16(vf1, pfr[ks], o1, 0, 0, 0);
  }
  __builtin_amdgcn_s_setprio(0);
}

__global__ __launch_bounds__(256)
void flash_attn(const __hip_bfloat16* __restrict__ q_s,
                const __hip_bfloat16* __restrict__ k_s,
                const __hip_bfloat16* __restrict__ vT_s,
                __hip_bfloat16* __restrict__ y_s)
{
  __shared__ __align__(16) __hip_bfloat16 sk [4][64*64];
  __shared__ __align__(16) __hip_bfloat16 svt[4][64*64];

  const int tid = threadIdx.x, w = tid>>6, l = tid&63;
  const int lq = l&31, h = l>>5, h4 = 4*h;
  const int bid = blockIdx.x;
  const int xcd = bid & 7, sl = (bid>>3) & 7, p = bid >> 6;
  const int bh = xcd*8 + sl;
  const size_t base = (size_t)bh * (2048*64);
  const int b = bh >> 4, hh = bh & 15;

  #pragma unroll 1
  for (int half = 0; half < 2; ++half){
    const int qbt = half ? p : (15 - p);
    const int q0w = qbt*128 + w*32;
    const int Jmax = 2*qbt + 1;            // iters 0..Jmax (count even)
    const int jd = q0w >> 6;               // diagonal tile for this wave
    const int qabs = q0w + lq;

    bf16x8 qf[4];
    #pragma unroll
    for (int ks = 0; ks < 4; ++ks)
      qf[ks] = *reinterpret_cast<const bf16x8*>(q_s + base + (size_t)qabs*64 + 16*ks + 8*h);

    f32x16 o0 = {}, o1 = {};
    f32x16 sA0, sA1, sB0, sB1;
    float mrun = -1e30f, lrun = 0.f;

    __syncthreads();                       // prior half's LDS reads complete
    stage_kv(k_s, vT_s, base, 0, sk[0], svt[0], w, l);
    stage_kv(k_s, vT_s, base, 1, sk[1], svt[1], w, l);

    // step macro: barrier; stage(j+2); QK(j)->SC; softmax+PV(j-1) from SP
    #define ATTN_STEP(J, SC0, SC1, SP0, SP1)                                   \
    {                                                                          \
      const int j_ = (J);                                                      \
      __syncthreads();                                                         \
      if (j_ + 2 <= Jmax)                                                      \
        stage_kv(k_s, vT_s, base, j_+2, sk[(j_+2)&3], svt[(j_+2)&3], w, l);    \
      if (j_ <= jd){                                                           \
        const __hip_bfloat16* skc = sk[j_&3];                                  \
        SC0 = (f32x16){}; SC1 = (f32x16){};                                    \
        __builtin_amdgcn_s_setprio(1);                                         \
        _Pragma("unroll")                                                      \
        for (int ks = 0; ks < 4; ++ks){                                        \
          bf16x8 kf0 = ldtile(skc, lq,      2*ks + h);                         \
          SC0 = __builtin_amdgcn_mfma_f32_32x32x16_bf16(kf0, qf[ks], SC0,0,0,0);\
          bf16x8 kf1 = ldtile(skc, 32 + lq, 2*ks + h);                         \
          SC1 = __builtin_amdgcn_mfma_f32_32x32x16_bf16(kf1, qf[ks], SC1,0,0,0);\
        }                                                                      \
        __builtin_amdgcn_s_setprio(0);                                         \
      }                                                                        \
      if (j_ >= 1 && j_ - 1 <= jd)                                             \
        softmax_pv(j_-1, jd, qabs, h4, lq, h, svt[(j_-1)&3],                   \
                   SP0, SP1, o0, o1, mrun, lrun);                              \
    }

    #pragma unroll 1
    for (int jj = 0; jj <= Jmax; jj += 2){
      ATTN_STEP(jj,   sA0, sA1, sB0, sB1);   // cur = A, prev = B
      ATTN_STEP(jj+1, sB0, sB1, sA0, sA1);   // cur = B, prev = A
    }
    #undef ATTN_STEP

    // epilogue: waves with jd == Jmax still owe softmax+PV of tile Jmax (in sB)
    if (jd == Jmax)
      softmax_pv(Jmax, jd, qabs, h4, lq, h, svt[Jmax&3],
                 sB0, sB1, o0, o1, mrun, lrun);

    // ---- y[b*2048 + q][hh*64 + d] ----
    const float inv = 1.f / lrun;
    __hip_bfloat16* yp = y_s + ((size_t)(b*2048 + qabs))*1024 + hh*64;
    #pragma unroll
    for (int i = 0; i < 8; ++i){
      const int d = (2*i & 3) + 8*(i>>1) + h4;   // r=2i -> (r&3)+8*(r>>2)+4h
      *reinterpret_cast<unsigned int*>(yp + d)      = cvtpk(o0[2*i]*inv, o0[2*i+1]*inv);
      *reinterpret_cast<unsigned int*>(yp + 32 + d) = cvtpk(o1[2*i]*inv, o1[2*i+1]*inv);
    }
  }
}

// ---------------- launch ----------------

extern "C" void kernel_launch(void* const* d_in, const int* in_sizes, int n_in,
                              void* d_out, int out_size, void* d_ws, size_t ws_size,
                              hipStream_t stream)
{
  const float* x      = (const float*)d_in[0];
  const float* w_attn = (const float*)d_in[1];
  const float* b_attn = (const float*)d_in[2];
  const float* w_proj = (const float*)d_in[3];
  const float* b_proj = (const float*)d_in[4];
  float* out = (float*)d_out;
  char* ws = (char*)d_ws;

  __hip_bfloat16* xb     = (__hip_bfloat16*)(ws + 0);          // 16 MB [8192][1024]
  __hip_bfloat16* wattnT = (__hip_bfloat16*)(ws + 16777216);   //  6 MB [3072][1024]
  __hip_bfloat16* wprojT = (__hip_bfloat16*)(ws + 23068672);   //  2 MB [1024][1024]
  __hip_bfloat16* q_s    = (__hip_bfloat16*)(ws + 25165824);   // 16 MB [64bh][2048][64]
  __hip_bfloat16* k_s    = (__hip_bfloat16*)(ws + 41943040);   // 16 MB [64bh][2048][64]
  __hip_bfloat16* vT_s   = (__hip_bfloat16*)(ws + 58720256);   // 16 MB [64bh][64][2048]
  __hip_bfloat16* y_s    = xb;                                  // reuse xb after gemm1

  f32_to_bf16_vec<<<2048, 256, 0, stream>>>(x, xb, 8388608/4);
  transpose_to_bf16<<<dim3(3072/32, 1024/32), 256, 0, stream>>>(w_attn, wattnT, 1024, 3072);
  transpose_to_bf16<<<dim3(1024/32, 1024/32), 256, 0, stream>>>(w_proj, wprojT, 1024, 1024);

  gemm_bf16<0><<<1536, 256, 0, stream>>>(
      xb, wattnT, b_attn, 8192, 3072, 1024, q_s, k_s, vT_s, (float*)nullptr);

  flash_attn<<<512, 256, 0, stream>>>(q_s, k_s, vT_s, y_s);

  gemm_bf16<1><<<512, 256, 0, stream>>>(
      y_s, wprojT, b_proj, 8192, 1024, 1024,
      (__hip_bfloat16*)nullptr, (__hip_bfloat16*)nullptr, (__hip_bfloat16*)nullptr, out);
}

// Round 10
// 219.977 us; speedup vs baseline: 1.1817x; 1.1817x over previous
//
#include <hip/hip_runtime.h>
#include <hip/hip_bf16.h>

// ---------------------------------------------------------------------------
// CausalSelfAttention: y = proj( softmax_causal( (xWqkv+b).q @ k^T / 8 ) @ v )
// B=4, T=2048, C=1024, H=16, D=64.  bf16 MFMA compute, fp32 accumulate.
// ---------------------------------------------------------------------------

typedef __attribute__((ext_vector_type(8)))  __bf16 bf16x8;
typedef __attribute__((ext_vector_type(2)))  float  f32x2;
typedef __attribute__((ext_vector_type(4)))  float  f32x4;
typedef __attribute__((ext_vector_type(16))) float  f32x16;
typedef __attribute__((ext_vector_type(4)))  unsigned int u32x4;

#define AS1C(p) ((const __attribute__((address_space(1))) unsigned int*)(p))
#define AS3(p)  ((__attribute__((address_space(3))) unsigned int*)(p))

__device__ __forceinline__ unsigned short f2bfu(float f){
  __hip_bfloat16 h = __float2bfloat16(f);
  return __builtin_bit_cast(unsigned short, h);
}

// v_permlane32_swap_b32: a.hi(lanes32-63) <-> b.lo(lanes0-31), both modified.
// ONLY safe when a and b hold distinct values (distinct vregs).
__device__ __forceinline__ void plswapu(unsigned int &a, unsigned int &b){
  asm("v_permlane32_swap_b32 %0, %1" : "+v"(a), "+v"(b));
}
// pack two f32 -> one u32 of 2 bf16 (lo = first arg)
__device__ __forceinline__ unsigned int cvtpk(float lo, float hi){
  unsigned int r;
  asm("v_cvt_pk_bf16_f32 %0, %1, %2" : "=v"(r) : "v"(lo), "v"(hi));
  return r;
}
__device__ __forceinline__ float max3f(float a, float b, float c){
  float r;
  asm("v_max3_f32 %0, %1, %2, %3" : "=v"(r) : "v"(a), "v"(b), "v"(c));
  return r;
}

// ---------------- conversion kernels ----------------

__global__ __launch_bounds__(256)
void f32_to_bf16_vec(const float* __restrict__ in, __hip_bfloat16* __restrict__ out, int n4){
  int stride = gridDim.x * blockDim.x;
  for (int i = blockIdx.x*blockDim.x + threadIdx.x; i < n4; i += stride){
    float4 v = reinterpret_cast<const float4*>(in)[i];
    ushort4 u;
    u.x = f2bfu(v.x); u.y = f2bfu(v.y); u.z = f2bfu(v.z); u.w = f2bfu(v.w);
    reinterpret_cast<ushort4*>(out)[i] = u;
  }
}

// in[R][C] fp32 -> out[C][R] bf16
__global__ __launch_bounds__(256)
void transpose_to_bf16(const float* __restrict__ in, __hip_bfloat16* __restrict__ out, int R, int C){
  __shared__ float tile[32][33];
  const int tx = threadIdx.x & 31, ty = threadIdx.x >> 5;
  const int c0 = blockIdx.x*32, r0 = blockIdx.y*32;
  for (int i = ty; i < 32; i += 8)
    tile[i][tx] = in[(size_t)(r0+i)*C + c0 + tx];
  __syncthreads();
  for (int i = ty; i < 32; i += 8)
    out[(size_t)(c0+i)*R + r0 + tx] = __float2bfloat16(tile[tx][i]);
}

// ---------------- bf16 GEMM (m97-style 128x128, BK=32) ----------------

#define QSCALE 0.1803368801111244f   // 0.125 * log2(e) -> softmax in exp2 space

template<int EPI>
__global__ __launch_bounds__(256)
void gemm_bf16(const __hip_bfloat16* __restrict__ A,
               const __hip_bfloat16* __restrict__ Bt,
               const float* __restrict__ bias,
               int M, int N, int K,
               __hip_bfloat16* __restrict__ q_s,
               __hip_bfloat16* __restrict__ k_s,
               __hip_bfloat16* __restrict__ vT_s,
               float* __restrict__ outf)
{
  __shared__ __align__(16) __hip_bfloat16 sA[128*32];
  __shared__ __align__(16) __hip_bfloat16 sB[128*32];
  const int tid = threadIdx.x, w = tid>>6, l = tid&63, g = l>>4, li = l&15;
  const int wm = w>>1, wn = w&1;

  const int nwg = gridDim.x, cpx = nwg >> 3;
  const int swz = (blockIdx.x & 7)*cpx + (blockIdx.x >> 3);
  const int nbx = N >> 7;
  const int m0 = (swz / nbx)*128, n0 = (swz % nbx)*128;

  f32x4 acc[4][4] = {};

  for (int k0 = 0; k0 < K; k0 += 32){
    __syncthreads();
    #pragma unroll
    for (int qq = 0; qq < 2; ++qq){
      const int c = qq*256 + w*64 + l;
      const int row = c>>2, kc = c&3;
      __builtin_amdgcn_global_load_lds(AS1C(A  + (size_t)(m0+row)*K + k0 + 8*kc),
                                       AS3(sA + (qq*256 + w*64)*8), 16, 0, 0);
      __builtin_amdgcn_global_load_lds(AS1C(Bt + (size_t)(n0+row)*K + k0 + 8*kc),
                                       AS3(sB + (qq*256 + w*64)*8), 16, 0, 0);
    }
    __syncthreads();

    bf16x8 af[4], bfr[4];
    #pragma unroll
    for (int mi = 0; mi < 4; ++mi)
      af[mi] = *reinterpret_cast<const bf16x8*>(sA + (wm*64 + mi*16 + li)*32 + 8*g);
    #pragma unroll
    for (int ni = 0; ni < 4; ++ni)
      bfr[ni] = *reinterpret_cast<const bf16x8*>(sB + (wn*64 + ni*16 + li)*32 + 8*g);
    #pragma unroll
    for (int mi = 0; mi < 4; ++mi)
      #pragma unroll
      for (int ni = 0; ni < 4; ++ni)
        acc[mi][ni] = __builtin_amdgcn_mfma_f32_16x16x32_bf16(af[mi], bfr[ni], acc[mi][ni], 0, 0, 0);
  }

  #pragma unroll
  for (int ni = 0; ni < 4; ++ni){
    const int col = n0 + wn*64 + ni*16 + li;
    const float bv = bias[col];
    #pragma unroll
    for (int mi = 0; mi < 4; ++mi){
      #pragma unroll
      for (int e = 0; e < 4; ++e){
        const int row = m0 + wm*64 + mi*16 + 4*g + e;
        const float val = acc[mi][ni][e] + bv;
        if (EPI == 0){
          const int three = col >> 10, h = (col >> 6) & 15, d = col & 63;
          const int b = row >> 11, t = row & 2047;
          const int bh = b*16 + h;
          if (three == 0)      q_s[((size_t)bh*2048 + t)*64 + d]  = __float2bfloat16(val*QSCALE);
          else if (three == 1) k_s[((size_t)bh*2048 + t)*64 + d]  = __float2bfloat16(val);
          else                 vT_s[((size_t)bh*64 + d)*2048 + t] = __float2bfloat16(val);  // V^T
        } else {
          outf[(size_t)row*N + col] = val;
        }
      }
    }
  }
}

// ---------------- flash attention ------------------------------------------
// R6 structure (4 waves x 32 q-rows, 128-row q-tile, halves (15-p) then (p),
// XCD-pinned bh, grid 512) with:
//  * TWO KV tiles per barrier interval over a 4-deep LDS ring (64 KB):
//      barrier; stage(jj+2, jj+3); compute(jj); compute(jj+1)
//    -> barriers halved, stage latency covered by ~2 tile-computes.
//  * tiles computed sequentially (S regs reused -> VGPR stays ~124, no cliff)
//  * packed-f32 softmax (v_pk_add_f32 trees) + v_max3_f32 max tree
//  * defer-max (THR=8 log2), setprio around MFMA clusters

__device__ __forceinline__ void stage_kv(const __hip_bfloat16* __restrict__ k_s,
                                         const __hip_bfloat16* __restrict__ vT_s,
                                         size_t base, int j,
                                         __hip_bfloat16* sk, __hip_bfloat16* svt,
                                         int w, int l)
{
  #pragma unroll
  for (int qq = 0; qq < 2; ++qq){
    const int c = qq*256 + w*64 + l;       // 16B chunk id (512 per 8KB tile)
    const int r = c>>3, cc = c&7;          // 8 chunks per 128B row
    __builtin_amdgcn_global_load_lds(AS1C(k_s  + base + (size_t)(j*64 + r)*64 + 8*(cc ^ (r&7))),
                                     AS3(sk  + (qq*256 + w*64)*8), 16, 0, 0);
    __builtin_amdgcn_global_load_lds(AS1C(vT_s + base + (size_t)r*2048 + j*64 + 8*(cc ^ (r&7))),
                                     AS3(svt + (qq*256 + w*64)*8), 16, 0, 0);
  }
}

__device__ __forceinline__ bf16x8 ldtile(const __hip_bfloat16* t, int row, int chunk){
  return *reinterpret_cast<const bf16x8*>(t + row*64 + ((chunk ^ (row&7))*8));
}

#define PFX(K) (((K)&1) ? pf2[(K)>>1].y : pf2[(K)>>1].x)

// full tile step: QK^T (swapped), packed softmax, PV (swapped)
__device__ __forceinline__ void tile_compute(
    int j, int jd, int qabs, int h4, int lq, int h,
    const __hip_bfloat16* skc, const __hip_bfloat16* svtc,
    const bf16x8* qf,
    f32x16& o0, f32x16& o1, float& mrun, float& lrun)
{
  // ---- QK^T swapped: St[kv][q], s0 = kv 0-31, s1 = kv 32-63 ----
  f32x16 s0 = {}, s1 = {};
  __builtin_amdgcn_s_setprio(1);
  #pragma unroll
  for (int ks = 0; ks < 4; ++ks){
    bf16x8 kf0 = ldtile(skc, lq,      2*ks + h);
    s0 = __builtin_amdgcn_mfma_f32_32x32x16_bf16(kf0, qf[ks], s0, 0, 0, 0);
    bf16x8 kf1 = ldtile(skc, 32 + lq, 2*ks + h);
    s1 = __builtin_amdgcn_mfma_f32_32x32x16_bf16(kf1, qf[ks], s1, 0, 0, 0);
  }
  __builtin_amdgcn_s_setprio(0);

  // ---- packed in-register softmax (lane owns q-row qabs) ----
  f32x2 pf2[16];
  #pragma unroll
  for (int i = 0; i < 8; ++i){
    pf2[i]     = (f32x2){ s0[2*i], s0[2*i+1] };
    pf2[8 + i] = (f32x2){ s1[2*i], s1[2*i+1] };
  }
  if (j == jd){                      // causal mask, diagonal tile only
    const int rel = qabs - 64*j;
    #pragma unroll
    for (int i = 0; i < 16; ++i){
      const int a = i >> 3;
      const int r0 = (i & 7)*2, r1 = r0 + 1;
      const int kv0 = 32*a + (r0&3) + 8*(r0>>2) + h4;
      const int kv1 = 32*a + (r1&3) + 8*(r1>>2) + h4;
      pf2[i].x = (kv0 <= rel) ? pf2[i].x : -1e30f;
      pf2[i].y = (kv1 <= rel) ? pf2[i].y : -1e30f;
    }
  }

  // max tree via v_max3 (17 ops)
  float t0 = max3f(PFX(0),PFX(1),PFX(2)),   t1 = max3f(PFX(3),PFX(4),PFX(5));
  float t2 = max3f(PFX(6),PFX(7),PFX(8)),   t3 = max3f(PFX(9),PFX(10),PFX(11));
  float t4 = max3f(PFX(12),PFX(13),PFX(14)),t5 = max3f(PFX(15),PFX(16),PFX(17));
  float t6 = max3f(PFX(18),PFX(19),PFX(20)),t7 = max3f(PFX(21),PFX(22),PFX(23));
  float t8 = max3f(PFX(24),PFX(25),PFX(26)),t9 = max3f(PFX(27),PFX(28),PFX(29));
  float t10 = fmaxf(PFX(30),PFX(31));
  float u0 = max3f(t0,t1,t2), u1 = max3f(t3,t4,t5), u2 = max3f(t6,t7,t8);
  float u3 = fmaxf(t9,t10);
  float pm = fmaxf(max3f(u0,u1,u2), u3);

  // defer-max (T13)
  if (!__all(pm - mrun <= 8.0f)){
    pm = fmaxf(pm, __shfl_xor(pm, 32));
    const float nm = fmaxf(mrun, pm);
    const float corr = exp2f(mrun - nm);
    mrun = nm;
    o0 *= corr; o1 *= corr;
    lrun *= corr;
  }

  // subtract (v_pk_add) + exp2
  const f32x2 negm = { -mrun, -mrun };
  #pragma unroll
  for (int i = 0; i < 16; ++i) pf2[i] = pf2[i] + negm;
  #pragma unroll
  for (int i = 0; i < 16; ++i){
    pf2[i].x = exp2f(pf2[i].x);
    pf2[i].y = exp2f(pf2[i].y);
  }

  // sum tree (v_pk_add) + cross-half combine
  f32x2 q8[8];
  #pragma unroll
  for (int i = 0; i < 8; ++i) q8[i] = pf2[i] + pf2[8+i];
  f32x2 q4a = q8[0]+q8[4], q4b = q8[1]+q8[5], q4c = q8[2]+q8[6], q4d = q8[3]+q8[7];
  f32x2 q2a = q4a+q4c, q2b = q4b+q4d;
  f32x2 q1 = q2a+q2b;
  float psum = q1.x + q1.y;
  psum += __shfl_xor(psum, 32);
  lrun += psum;

  // P -> bf16 B-frags (cvt_pk + permlane32_swap, distinct operands)
  unsigned int wds[16];
  #pragma unroll
  for (int k = 0; k < 16; ++k) wds[k] = cvtpk(pf2[k].x, pf2[k].y);
  #pragma unroll
  for (int a = 0; a < 2; ++a)
    #pragma unroll
    for (int bl = 0; bl < 2; ++bl){
      plswapu(wds[a*8 + 4*bl    ], wds[a*8 + 4*bl + 2]);
      plswapu(wds[a*8 + 4*bl + 1], wds[a*8 + 4*bl + 3]);
    }
  bf16x8 pfr[4];
  #pragma unroll
  for (int B = 0; B < 4; ++B){
    u32x4 t = { wds[4*B], wds[4*B+1], wds[4*B+2], wds[4*B+3] };
    pfr[B] = __builtin_bit_cast(bf16x8, t);
  }

  // ---- PV swapped: O[d][q] ----
  __builtin_amdgcn_s_setprio(1);
  #pragma unroll
  for (int ks = 0; ks < 4; ++ks){
    bf16x8 vf0 = ldtile(svtc, lq,      2*ks + h);
    o0 = __builtin_amdgcn_mfma_f32_32x32x16_bf16(vf0, pfr[ks], o0, 0, 0, 0);
    bf16x8 vf1 = ldtile(svtc, 32 + lq, 2*ks + h);
    o1 = __builtin_amdgcn_mfma_f32_32x32x16_bf16(vf1, pfr[ks], o1, 0, 0, 0);
  }
  __builtin_amdgcn_s_setprio(0);
}

__global__ __launch_bounds__(256)
void flash_attn(const __hip_bfloat16* __restrict__ q_s,
                const __hip_bfloat16* __restrict__ k_s,
                const __hip_bfloat16* __restrict__ vT_s,
                __hip_bfloat16* __restrict__ y_s)
{
  __shared__ __align__(16) __hip_bfloat16 sk [4][64*64];
  __shared__ __align__(16) __hip_bfloat16 svt[4][64*64];

  const int tid = threadIdx.x, w = tid>>6, l = tid&63;
  const int lq = l&31, h = l>>5, h4 = 4*h;
  const int bid = blockIdx.x;
  const int xcd = bid & 7, sl = (bid>>3) & 7, p = bid >> 6;
  const int bh = xcd*8 + sl;
  const size_t base = (size_t)bh * (2048*64);
  const int b = bh >> 4, hh = bh & 15;

  #pragma unroll 1
  for (int half = 0; half < 2; ++half){
    const int qbt = half ? p : (15 - p);
    const int q0w = qbt*128 + w*32;
    const int Jmax = 2*qbt + 1;            // odd -> iteration count even
    const int jd = q0w >> 6;               // diagonal tile for this wave
    const int qabs = q0w + lq;

    bf16x8 qf[4];
    #pragma unroll
    for (int ks = 0; ks < 4; ++ks)
      qf[ks] = *reinterpret_cast<const bf16x8*>(q_s + base + (size_t)qabs*64 + 16*ks + 8*h);

    f32x16 o0 = {}, o1 = {};
    float mrun = -1e30f, lrun = 0.f;

    __syncthreads();                       // prior half's LDS reads complete
    stage_kv(k_s, vT_s, base, 0, sk[0], svt[0], w, l);
    stage_kv(k_s, vT_s, base, 1, sk[1], svt[1], w, l);

    #pragma unroll 1
    for (int jj = 0; jj <= Jmax; jj += 2){
      __syncthreads();                     // buffers jj, jj+1 staged
      if (jj + 2 <= Jmax)
        stage_kv(k_s, vT_s, base, jj+2, sk[(jj+2)&3], svt[(jj+2)&3], w, l);
      if (jj + 3 <= Jmax)
        stage_kv(k_s, vT_s, base, jj+3, sk[(jj+3)&3], svt[(jj+3)&3], w, l);

      if (jj <= jd)
        tile_compute(jj,   jd, qabs, h4, lq, h, sk[jj&3],     svt[jj&3],
                     qf, o0, o1, mrun, lrun);
      if (jj + 1 <= jd)
        tile_compute(jj+1, jd, qabs, h4, lq, h, sk[(jj+1)&3], svt[(jj+1)&3],
                     qf, o0, o1, mrun, lrun);
    }

    // ---- epilogue: y[b*2048 + q][hh*64 + d] ----
    const float inv = 1.f / lrun;
    __hip_bfloat16* yp = y_s + ((size_t)(b*2048 + qabs))*1024 + hh*64;
    #pragma unroll
    for (int i = 0; i < 8; ++i){
      const int d = (2*i & 3) + 8*(i>>1) + h4;   // r=2i -> (r&3)+8*(r>>2)+4h
      *reinterpret_cast<unsigned int*>(yp + d)      = cvtpk(o0[2*i]*inv, o0[2*i+1]*inv);
      *reinterpret_cast<unsigned int*>(yp + 32 + d) = cvtpk(o1[2*i]*inv, o1[2*i+1]*inv);
    }
  }
}

// ---------------- launch ----------------

extern "C" void kernel_launch(void* const* d_in, const int* in_sizes, int n_in,
                              void* d_out, int out_size, void* d_ws, size_t ws_size,
                              hipStream_t stream)
{
  const float* x      = (const float*)d_in[0];
  const float* w_attn = (const float*)d_in[1];
  const float* b_attn = (const float*)d_in[2];
  const float* w_proj = (const float*)d_in[3];
  const float* b_proj = (const float*)d_in[4];
  float* out = (float*)d_out;
  char* ws = (char*)d_ws;

  __hip_bfloat16* xb     = (__hip_bfloat16*)(ws + 0);          // 16 MB [8192][1024]
  __hip_bfloat16* wattnT = (__hip_bfloat16*)(ws + 16777216);   //  6 MB [3072][1024]
  __hip_bfloat16* wprojT = (__hip_bfloat16*)(ws + 23068672);   //  2 MB [1024][1024]
  __hip_bfloat16* q_s    = (__hip_bfloat16*)(ws + 25165824);   // 16 MB [64bh][2048][64]
  __hip_bfloat16* k_s    = (__hip_bfloat16*)(ws + 41943040);   // 16 MB [64bh][2048][64]
  __hip_bfloat16* vT_s   = (__hip_bfloat16*)(ws + 58720256);   // 16 MB [64bh][64][2048]
  __hip_bfloat16* y_s    = xb;                                  // reuse xb after gemm1

  f32_to_bf16_vec<<<2048, 256, 0, stream>>>(x, xb, 8388608/4);
  transpose_to_bf16<<<dim3(3072/32, 1024/32), 256, 0, stream>>>(w_attn, wattnT, 1024, 3072);
  transpose_to_bf16<<<dim3(1024/32, 1024/32), 256, 0, stream>>>(w_proj, wprojT, 1024, 1024);

  gemm_bf16<0><<<1536, 256, 0, stream>>>(
      xb, wattnT, b_attn, 8192, 3072, 1024, q_s, k_s, vT_s, (float*)nullptr);

  flash_attn<<<512, 256, 0, stream>>>(q_s, k_s, vT_s, y_s);

  gemm_bf16<1><<<512, 256, 0, stream>>>(
      y_s, wprojT, b_proj, 8192, 1024, 1024,
      (__hip_bfloat16*)nullptr, (__hip_bfloat16*)nullptr, (__hip_bfloat16*)nullptr, out);
}

// Round 11
// 213.691 us; speedup vs baseline: 1.2164x; 1.0294x over previous
//
#include <hip/hip_runtime.h>
#include <hip/hip_bf16.h>

// ---------------------------------------------------------------------------
// CausalSelfAttention: y = proj( softmax_causal( (xWqkv+b).q @ k^T / 8 ) @ v )
// B=4, T=2048, C=1024, H=16, D=64.  bf16 MFMA compute, fp32 accumulate.
// ---------------------------------------------------------------------------

typedef __attribute__((ext_vector_type(8)))  __bf16 bf16x8;
typedef __attribute__((ext_vector_type(2)))  float  f32x2;
typedef __attribute__((ext_vector_type(4)))  float  f32x4;
typedef __attribute__((ext_vector_type(16))) float  f32x16;
typedef __attribute__((ext_vector_type(4)))  unsigned int u32x4;

#define AS1C(p) ((const __attribute__((address_space(1))) unsigned int*)(p))
#define AS3(p)  ((__attribute__((address_space(3))) unsigned int*)(p))

__device__ __forceinline__ unsigned short f2bfu(float f){
  __hip_bfloat16 h = __float2bfloat16(f);
  return __builtin_bit_cast(unsigned short, h);
}

// v_permlane32_swap_b32: a.hi(lanes32-63) <-> b.lo(lanes0-31), both modified.
// ONLY safe when a and b hold distinct values (distinct vregs).
__device__ __forceinline__ void plswapu(unsigned int &a, unsigned int &b){
  asm("v_permlane32_swap_b32 %0, %1" : "+v"(a), "+v"(b));
}
// pack two f32 -> one u32 of 2 bf16 (lo = first arg)
__device__ __forceinline__ unsigned int cvtpk(float lo, float hi){
  unsigned int r;
  asm("v_cvt_pk_bf16_f32 %0, %1, %2" : "=v"(r) : "v"(lo), "v"(hi));
  return r;
}
__device__ __forceinline__ float max3f(float a, float b, float c){
  float r;
  asm("v_max3_f32 %0, %1, %2, %3" : "=v"(r) : "v"(a), "v"(b), "v"(c));
  return r;
}

// ---------------- conversion kernels ----------------

__global__ __launch_bounds__(256)
void f32_to_bf16_vec(const float* __restrict__ in, __hip_bfloat16* __restrict__ out, int n4){
  int stride = gridDim.x * blockDim.x;
  for (int i = blockIdx.x*blockDim.x + threadIdx.x; i < n4; i += stride){
    float4 v = reinterpret_cast<const float4*>(in)[i];
    ushort4 u;
    u.x = f2bfu(v.x); u.y = f2bfu(v.y); u.z = f2bfu(v.z); u.w = f2bfu(v.w);
    reinterpret_cast<ushort4*>(out)[i] = u;
  }
}

// in[R][C] fp32 -> out[C][R] bf16
__global__ __launch_bounds__(256)
void transpose_to_bf16(const float* __restrict__ in, __hip_bfloat16* __restrict__ out, int R, int C){
  __shared__ float tile[32][33];
  const int tx = threadIdx.x & 31, ty = threadIdx.x >> 5;
  const int c0 = blockIdx.x*32, r0 = blockIdx.y*32;
  for (int i = ty; i < 32; i += 8)
    tile[i][tx] = in[(size_t)(r0+i)*C + c0 + tx];
  __syncthreads();
  for (int i = ty; i < 32; i += 8)
    out[(size_t)(c0+i)*R + r0 + tx] = __float2bfloat16(tile[tx][i]);
}

// ---------------- bf16 GEMM (128x128, BK=32, double-buffered prefetch) ------
// A[M][K] bf16 row-major, Bt[N][K] bf16 row-major.  XCD-bijective swizzle.
// T3-minimum loop: ONE barrier per K-tile; stage(kt+1) issued before
// compute(kt) so MFMA/ds_read cover the global->LDS latency.

#define QSCALE 0.1803368801111244f   // 0.125 * log2(e) -> softmax in exp2 space

__device__ __forceinline__ void stage_ab(const __hip_bfloat16* __restrict__ A,
                                         const __hip_bfloat16* __restrict__ Bt,
                                         int m0, int n0, int K, int kt,
                                         __hip_bfloat16* sA, __hip_bfloat16* sB,
                                         int w, int l)
{
  const int k0 = kt*32;
  #pragma unroll
  for (int qq = 0; qq < 2; ++qq){
    const int c = qq*256 + w*64 + l;        // 16B chunk id, 512 per tile
    const int row = c>>2, kc = c&3;         // 4 chunks per 32-elem row
    __builtin_amdgcn_global_load_lds(AS1C(A  + (size_t)(m0+row)*K + k0 + 8*kc),
                                     AS3(sA + (qq*256 + w*64)*8), 16, 0, 0);
    __builtin_amdgcn_global_load_lds(AS1C(Bt + (size_t)(n0+row)*K + k0 + 8*kc),
                                     AS3(sB + (qq*256 + w*64)*8), 16, 0, 0);
  }
}

template<int EPI>
__global__ __launch_bounds__(256)
void gemm_bf16(const __hip_bfloat16* __restrict__ A,
               const __hip_bfloat16* __restrict__ Bt,
               const float* __restrict__ bias,
               int M, int N, int K,
               __hip_bfloat16* __restrict__ q_s,
               __hip_bfloat16* __restrict__ k_s,
               __hip_bfloat16* __restrict__ vT_s,
               float* __restrict__ outf)
{
  __shared__ __align__(16) __hip_bfloat16 sA[2][128*32];
  __shared__ __align__(16) __hip_bfloat16 sB[2][128*32];
  const int tid = threadIdx.x, w = tid>>6, l = tid&63, g = l>>4, li = l&15;
  const int wm = w>>1, wn = w&1;

  const int nwg = gridDim.x, cpx = nwg >> 3;
  const int swz = (blockIdx.x & 7)*cpx + (blockIdx.x >> 3);
  const int nbx = N >> 7;
  const int m0 = (swz / nbx)*128, n0 = (swz % nbx)*128;

  f32x4 acc[4][4] = {};

  const int NT = K >> 5;
  stage_ab(A, Bt, m0, n0, K, 0, sA[0], sB[0], w, l);
  int cur = 0;

  for (int kt = 0; kt < NT; ++kt){
    __syncthreads();                       // buf[cur] staged (vmcnt drained)
    if (kt + 1 < NT)
      stage_ab(A, Bt, m0, n0, K, kt+1, sA[cur^1], sB[cur^1], w, l);

    bf16x8 af[4], bfr[4];
    #pragma unroll
    for (int mi = 0; mi < 4; ++mi)
      af[mi] = *reinterpret_cast<const bf16x8*>(sA[cur] + (wm*64 + mi*16 + li)*32 + 8*g);
    #pragma unroll
    for (int ni = 0; ni < 4; ++ni)
      bfr[ni] = *reinterpret_cast<const bf16x8*>(sB[cur] + (wn*64 + ni*16 + li)*32 + 8*g);
    #pragma unroll
    for (int mi = 0; mi < 4; ++mi)
      #pragma unroll
      for (int ni = 0; ni < 4; ++ni)
        acc[mi][ni] = __builtin_amdgcn_mfma_f32_16x16x32_bf16(af[mi], bfr[ni], acc[mi][ni], 0, 0, 0);
    cur ^= 1;
  }

  #pragma unroll
  for (int ni = 0; ni < 4; ++ni){
    const int col = n0 + wn*64 + ni*16 + li;
    const float bv = bias[col];
    #pragma unroll
    for (int mi = 0; mi < 4; ++mi){
      #pragma unroll
      for (int e = 0; e < 4; ++e){
        const int row = m0 + wm*64 + mi*16 + 4*g + e;
        const float val = acc[mi][ni][e] + bv;
        if (EPI == 0){
          const int three = col >> 10, h = (col >> 6) & 15, d = col & 63;
          const int b = row >> 11, t = row & 2047;
          const int bh = b*16 + h;
          if (three == 0)      q_s[((size_t)bh*2048 + t)*64 + d]  = __float2bfloat16(val*QSCALE);
          else if (three == 1) k_s[((size_t)bh*2048 + t)*64 + d]  = __float2bfloat16(val);
          else                 vT_s[((size_t)bh*64 + d)*2048 + t] = __float2bfloat16(val);  // V^T
        } else {
          outf[(size_t)row*N + col] = val;
        }
      }
    }
  }
}

// ---------------- flash attention (R10 structure, unchanged) ----------------
// 4 waves x 32 q-rows, 128-row q-tile, halves (15-p) then (p), XCD-pinned bh,
// grid 512. TWO KV tiles per barrier over a 4-deep LDS ring; packed softmax;
// defer-max; setprio around MFMA clusters.

__device__ __forceinline__ void stage_kv(const __hip_bfloat16* __restrict__ k_s,
                                         const __hip_bfloat16* __restrict__ vT_s,
                                         size_t base, int j,
                                         __hip_bfloat16* sk, __hip_bfloat16* svt,
                                         int w, int l)
{
  #pragma unroll
  for (int qq = 0; qq < 2; ++qq){
    const int c = qq*256 + w*64 + l;       // 16B chunk id (512 per 8KB tile)
    const int r = c>>3, cc = c&7;          // 8 chunks per 128B row
    __builtin_amdgcn_global_load_lds(AS1C(k_s  + base + (size_t)(j*64 + r)*64 + 8*(cc ^ (r&7))),
                                     AS3(sk  + (qq*256 + w*64)*8), 16, 0, 0);
    __builtin_amdgcn_global_load_lds(AS1C(vT_s + base + (size_t)r*2048 + j*64 + 8*(cc ^ (r&7))),
                                     AS3(svt + (qq*256 + w*64)*8), 16, 0, 0);
  }
}

__device__ __forceinline__ bf16x8 ldtile(const __hip_bfloat16* t, int row, int chunk){
  return *reinterpret_cast<const bf16x8*>(t + row*64 + ((chunk ^ (row&7))*8));
}

#define PFX(K) (((K)&1) ? pf2[(K)>>1].y : pf2[(K)>>1].x)

// full tile step: QK^T (swapped), packed softmax, PV (swapped)
__device__ __forceinline__ void tile_compute(
    int j, int jd, int qabs, int h4, int lq, int h,
    const __hip_bfloat16* skc, const __hip_bfloat16* svtc,
    const bf16x8* qf,
    f32x16& o0, f32x16& o1, float& mrun, float& lrun)
{
  // ---- QK^T swapped: St[kv][q], s0 = kv 0-31, s1 = kv 32-63 ----
  f32x16 s0 = {}, s1 = {};
  __builtin_amdgcn_s_setprio(1);
  #pragma unroll
  for (int ks = 0; ks < 4; ++ks){
    bf16x8 kf0 = ldtile(skc, lq,      2*ks + h);
    s0 = __builtin_amdgcn_mfma_f32_32x32x16_bf16(kf0, qf[ks], s0, 0, 0, 0);
    bf16x8 kf1 = ldtile(skc, 32 + lq, 2*ks + h);
    s1 = __builtin_amdgcn_mfma_f32_32x32x16_bf16(kf1, qf[ks], s1, 0, 0, 0);
  }
  __builtin_amdgcn_s_setprio(0);

  // ---- packed in-register softmax (lane owns q-row qabs) ----
  f32x2 pf2[16];
  #pragma unroll
  for (int i = 0; i < 8; ++i){
    pf2[i]     = (f32x2){ s0[2*i], s0[2*i+1] };
    pf2[8 + i] = (f32x2){ s1[2*i], s1[2*i+1] };
  }
  if (j == jd){                      // causal mask, diagonal tile only
    const int rel = qabs - 64*j;
    #pragma unroll
    for (int i = 0; i < 16; ++i){
      const int a = i >> 3;
      const int r0 = (i & 7)*2, r1 = r0 + 1;
      const int kv0 = 32*a + (r0&3) + 8*(r0>>2) + h4;
      const int kv1 = 32*a + (r1&3) + 8*(r1>>2) + h4;
      pf2[i].x = (kv0 <= rel) ? pf2[i].x : -1e30f;
      pf2[i].y = (kv1 <= rel) ? pf2[i].y : -1e30f;
    }
  }

  // max tree via v_max3 (17 ops)
  float t0 = max3f(PFX(0),PFX(1),PFX(2)),   t1 = max3f(PFX(3),PFX(4),PFX(5));
  float t2 = max3f(PFX(6),PFX(7),PFX(8)),   t3 = max3f(PFX(9),PFX(10),PFX(11));
  float t4 = max3f(PFX(12),PFX(13),PFX(14)),t5 = max3f(PFX(15),PFX(16),PFX(17));
  float t6 = max3f(PFX(18),PFX(19),PFX(20)),t7 = max3f(PFX(21),PFX(22),PFX(23));
  float t8 = max3f(PFX(24),PFX(25),PFX(26)),t9 = max3f(PFX(27),PFX(28),PFX(29));
  float t10 = fmaxf(PFX(30),PFX(31));
  float u0 = max3f(t0,t1,t2), u1 = max3f(t3,t4,t5), u2 = max3f(t6,t7,t8);
  float u3 = fmaxf(t9,t10);
  float pm = fmaxf(max3f(u0,u1,u2), u3);

  // defer-max (T13)
  if (!__all(pm - mrun <= 8.0f)){
    pm = fmaxf(pm, __shfl_xor(pm, 32));
    const float nm = fmaxf(mrun, pm);
    const float corr = exp2f(mrun - nm);
    mrun = nm;
    o0 *= corr; o1 *= corr;
    lrun *= corr;
  }

  // subtract (v_pk_add) + exp2
  const f32x2 negm = { -mrun, -mrun };
  #pragma unroll
  for (int i = 0; i < 16; ++i) pf2[i] = pf2[i] + negm;
  #pragma unroll
  for (int i = 0; i < 16; ++i){
    pf2[i].x = exp2f(pf2[i].x);
    pf2[i].y = exp2f(pf2[i].y);
  }

  // sum tree (v_pk_add) + cross-half combine
  f32x2 q8[8];
  #pragma unroll
  for (int i = 0; i < 8; ++i) q8[i] = pf2[i] + pf2[8+i];
  f32x2 q4a = q8[0]+q8[4], q4b = q8[1]+q8[5], q4c = q8[2]+q8[6], q4d = q8[3]+q8[7];
  f32x2 q2a = q4a+q4c, q2b = q4b+q4d;
  f32x2 q1 = q2a+q2b;
  float psum = q1.x + q1.y;
  psum += __shfl_xor(psum, 32);
  lrun += psum;

  // P -> bf16 B-frags (cvt_pk + permlane32_swap, distinct operands)
  unsigned int wds[16];
  #pragma unroll
  for (int k = 0; k < 16; ++k) wds[k] = cvtpk(pf2[k].x, pf2[k].y);
  #pragma unroll
  for (int a = 0; a < 2; ++a)
    #pragma unroll
    for (int bl = 0; bl < 2; ++bl){
      plswapu(wds[a*8 + 4*bl    ], wds[a*8 + 4*bl + 2]);
      plswapu(wds[a*8 + 4*bl + 1], wds[a*8 + 4*bl + 3]);
    }
  bf16x8 pfr[4];
  #pragma unroll
  for (int B = 0; B < 4; ++B){
    u32x4 t = { wds[4*B], wds[4*B+1], wds[4*B+2], wds[4*B+3] };
    pfr[B] = __builtin_bit_cast(bf16x8, t);
  }

  // ---- PV swapped: O[d][q] ----
  __builtin_amdgcn_s_setprio(1);
  #pragma unroll
  for (int ks = 0; ks < 4; ++ks){
    bf16x8 vf0 = ldtile(svtc, lq,      2*ks + h);
    o0 = __builtin_amdgcn_mfma_f32_32x32x16_bf16(vf0, pfr[ks], o0, 0, 0, 0);
    bf16x8 vf1 = ldtile(svtc, 32 + lq, 2*ks + h);
    o1 = __builtin_amdgcn_mfma_f32_32x32x16_bf16(vf1, pfr[ks], o1, 0, 0, 0);
  }
  __builtin_amdgcn_s_setprio(0);
}

__global__ __launch_bounds__(256)
void flash_attn(const __hip_bfloat16* __restrict__ q_s,
                const __hip_bfloat16* __restrict__ k_s,
                const __hip_bfloat16* __restrict__ vT_s,
                __hip_bfloat16* __restrict__ y_s)
{
  __shared__ __align__(16) __hip_bfloat16 sk [4][64*64];
  __shared__ __align__(16) __hip_bfloat16 svt[4][64*64];

  const int tid = threadIdx.x, w = tid>>6, l = tid&63;
  const int lq = l&31, h = l>>5, h4 = 4*h;
  const int bid = blockIdx.x;
  const int xcd = bid & 7, sl = (bid>>3) & 7, p = bid >> 6;
  const int bh = xcd*8 + sl;
  const size_t base = (size_t)bh * (2048*64);
  const int b = bh >> 4, hh = bh & 15;

  #pragma unroll 1
  for (int half = 0; half < 2; ++half){
    const int qbt = half ? p : (15 - p);
    const int q0w = qbt*128 + w*32;
    const int Jmax = 2*qbt + 1;            // odd -> iteration count even
    const int jd = q0w >> 6;               // diagonal tile for this wave
    const int qabs = q0w + lq;

    bf16x8 qf[4];
    #pragma unroll
    for (int ks = 0; ks < 4; ++ks)
      qf[ks] = *reinterpret_cast<const bf16x8*>(q_s + base + (size_t)qabs*64 + 16*ks + 8*h);

    f32x16 o0 = {}, o1 = {};
    float mrun = -1e30f, lrun = 0.f;

    __syncthreads();                       // prior half's LDS reads complete
    stage_kv(k_s, vT_s, base, 0, sk[0], svt[0], w, l);
    stage_kv(k_s, vT_s, base, 1, sk[1], svt[1], w, l);

    #pragma unroll 1
    for (int jj = 0; jj <= Jmax; jj += 2){
      __syncthreads();                     // buffers jj, jj+1 staged
      if (jj + 2 <= Jmax)
        stage_kv(k_s, vT_s, base, jj+2, sk[(jj+2)&3], svt[(jj+2)&3], w, l);
      if (jj + 3 <= Jmax)
        stage_kv(k_s, vT_s, base, jj+3, sk[(jj+3)&3], svt[(jj+3)&3], w, l);

      if (jj <= jd)
        tile_compute(jj,   jd, qabs, h4, lq, h, sk[jj&3],     svt[jj&3],
                     qf, o0, o1, mrun, lrun);
      if (jj + 1 <= jd)
        tile_compute(jj+1, jd, qabs, h4, lq, h, sk[(jj+1)&3], svt[(jj+1)&3],
                     qf, o0, o1, mrun, lrun);
    }

    // ---- epilogue: y[b*2048 + q][hh*64 + d] ----
    const float inv = 1.f / lrun;
    __hip_bfloat16* yp = y_s + ((size_t)(b*2048 + qabs))*1024 + hh*64;
    #pragma unroll
    for (int i = 0; i < 8; ++i){
      const int d = (2*i & 3) + 8*(i>>1) + h4;   // r=2i -> (r&3)+8*(r>>2)+4h
      *reinterpret_cast<unsigned int*>(yp + d)      = cvtpk(o0[2*i]*inv, o0[2*i+1]*inv);
      *reinterpret_cast<unsigned int*>(yp + 32 + d) = cvtpk(o1[2*i]*inv, o1[2*i+1]*inv);
    }
  }
}

// ---------------- launch ----------------

extern "C" void kernel_launch(void* const* d_in, const int* in_sizes, int n_in,
                              void* d_out, int out_size, void* d_ws, size_t ws_size,
                              hipStream_t stream)
{
  const float* x      = (const float*)d_in[0];
  const float* w_attn = (const float*)d_in[1];
  const float* b_attn = (const float*)d_in[2];
  const float* w_proj = (const float*)d_in[3];
  const float* b_proj = (const float*)d_in[4];
  float* out = (float*)d_out;
  char* ws = (char*)d_ws;

  __hip_bfloat16* xb     = (__hip_bfloat16*)(ws + 0);          // 16 MB [8192][1024]
  __hip_bfloat16* wattnT = (__hip_bfloat16*)(ws + 16777216);   //  6 MB [3072][1024]
  __hip_bfloat16* wprojT = (__hip_bfloat16*)(ws + 23068672);   //  2 MB [1024][1024]
  __hip_bfloat16* q_s    = (__hip_bfloat16*)(ws + 25165824);   // 16 MB [64bh][2048][64]
  __hip_bfloat16* k_s    = (__hip_bfloat16*)(ws + 41943040);   // 16 MB [64bh][2048][64]
  __hip_bfloat16* vT_s   = (__hip_bfloat16*)(ws + 58720256);   // 16 MB [64bh][64][2048]
  __hip_bfloat16* y_s    = xb;                                  // reuse xb after gemm1

  f32_to_bf16_vec<<<2048, 256, 0, stream>>>(x, xb, 8388608/4);
  transpose_to_bf16<<<dim3(3072/32, 1024/32), 256, 0, stream>>>(w_attn, wattnT, 1024, 3072);
  transpose_to_bf16<<<dim3(1024/32, 1024/32), 256, 0, stream>>>(w_proj, wprojT, 1024, 1024);

  gemm_bf16<0><<<1536, 256, 0, stream>>>(
      xb, wattnT, b_attn, 8192, 3072, 1024, q_s, k_s, vT_s, (float*)nullptr);

  flash_attn<<<512, 256, 0, stream>>>(q_s, k_s, vT_s, y_s);

  gemm_bf16<1><<<512, 256, 0, stream>>>(
      y_s, wprojT, b_proj, 8192, 1024, 1024,
      (__hip_bfloat16*)nullptr, (__hip_bfloat16*)nullptr, (__hip_bfloat16*)nullptr, out);
}